// Round 5
// baseline (90.838 us; speedup 1.0000x reference)
//
#include <hip/hip_runtime.h>

typedef __attribute__((ext_vector_type(8))) short short8v;
typedef __attribute__((ext_vector_type(4))) float f32x4;

// ---------- helpers ----------
__device__ inline unsigned short f2b(float f) {
    unsigned u = __builtin_bit_cast(unsigned, f);
    unsigned r = u + 0x7fffu + ((u >> 16) & 1u);
    return (unsigned short)(r >> 16);
}
__device__ inline float blo(unsigned u) {
    return __builtin_bit_cast(float, u << 16);
}
__device__ inline float bhi(unsigned u) {
    return __builtin_bit_cast(float, u & 0xffff0000u);
}
__device__ inline void gload16(const void* g, void* l) {
    __builtin_amdgcn_global_load_lds(
        (const __attribute__((address_space(1))) void*)g,
        (__attribute__((address_space(3))) void*)l, 16, 0, 0);
}

// ---------- prep: f32->bf16 conversion + ext prefixes + row maps ----------
__global__ __launch_bounds__(256)
void prep_kernel(const float* __restrict__ x, const float* __restrict__ wkv,
                 const float* __restrict__ wq, const float* __restrict__ wp,
                 const float* __restrict__ buf, const int* __restrict__ sl,
                 const float* __restrict__ bkv, const float* __restrict__ bq,
                 short* __restrict__ dst, short* __restrict__ ext,
                 int* __restrict__ extrow, int* __restrict__ destrow,
                 float* __restrict__ biascat,
                 long n0, long n1, long n2, long n3, long n4,
                 int T, int Bn, int MAXL, int EK, int NKVQ)
{
    long gid = (long)blockIdx.x * blockDim.x + threadIdx.x;
    long e = gid * 8;
    if (e < n3) {
        const float* s; long off;
        if (e < n0)      { s = x;   off = e; }
        else if (e < n1) { s = wkv; off = e - n0; }
        else if (e < n2) { s = wq;  off = e - n1; }
        else             { s = wp;  off = e - n2; }
        float4 a = *(const float4*)(s + off);
        float4 b = *(const float4*)(s + off + 4);
        short8v o;
        o[0] = (short)f2b(a.x); o[1] = (short)f2b(a.y);
        o[2] = (short)f2b(a.z); o[3] = (short)f2b(a.w);
        o[4] = (short)f2b(b.x); o[5] = (short)f2b(b.y);
        o[6] = (short)f2b(b.z); o[7] = (short)f2b(b.w);
        *(short8v*)(dst + e) = o;
    } else if (e < n4) {
        // learned buffer rows -> 31-row prefix of every segment in ext
        long off = e - n3;
        int brow = (int)(off / EK);
        int bcol = (int)(off % EK);
        float4 a = *(const float4*)(buf + off);
        float4 b = *(const float4*)(buf + off + 4);
        short8v o;
        o[0] = (short)f2b(a.x); o[1] = (short)f2b(a.y);
        o[2] = (short)f2b(a.z); o[3] = (short)f2b(a.w);
        o[4] = (short)f2b(b.x); o[5] = (short)f2b(b.y);
        o[6] = (short)f2b(b.z); o[7] = (short)f2b(b.w);
        int start = 0;
        for (int s = 0; s < 8; ++s) {
            int dr = 31 * s + start + brow;
            *(short8v*)&ext[(size_t)dr * EK + bcol] = o;
            start += sl[s];
        }
    }
    if (gid < T) {
        int start = 0, seg = 0, jloc = 0;
        for (int i = 0; i < Bn; ++i) {
            int len = sl[i];
            if (gid >= start && gid < start + len) { seg = i; jloc = (int)gid - start; }
            start += len;
        }
        destrow[gid] = seg * MAXL + jloc;
        extrow[gid]  = 31 * (seg + 1) + (int)gid;
    }
    if (gid < NKVQ) {
        biascat[gid] = (gid < EK) ? bkv[gid] : bq[gid - EK];
    }
}

// ---------- zero only the padding rows of y ----------
__global__ __launch_bounds__(256)
void padzero_kernel(float* __restrict__ y, const int* __restrict__ sl,
                    int MAXL, int E)
{
    int row = blockIdx.x;
    int seg = row / MAXL, pos = row - seg * MAXL;
    if (pos < sl[seg]) return;
    float4 z = {0.f, 0.f, 0.f, 0.f};
    *(float4*)&y[(size_t)row * E + threadIdx.x * 4] = z;
}

// ---------- bf16 GEMM: C[M,N] = A[M,K] @ B[N,K]^T + bias ----------
// MODE 0: split write: col<1536 -> bf16 ext[extrow[row]][col]; else bf16 q[row][col-1536]
// MODE 1: f32 rows scattered: y[rowmap[row]][col]
template<int MODE>
__global__ __launch_bounds__(256)
void gemm_bt(const short* __restrict__ A, const short* __restrict__ Bm,
             const float* __restrict__ bias,
             short* __restrict__ C0, short* __restrict__ C1,
             float* __restrict__ Cf, const int* __restrict__ rowmap,
             int M, int N, int Kd)
{
    __shared__ short lA[128 * 32];
    __shared__ short lB[128 * 32];
    int nb = N >> 7;
    // XCD-aware bijective swizzle (grid is a multiple of 8)
    int bid0 = blockIdx.x;
    int bid = (bid0 & 7) * ((int)gridDim.x >> 3) + (bid0 >> 3);
    int m0 = (bid / nb) << 7, n0 = (bid % nb) << 7;
    int tid = threadIdx.x;
    int lane = tid & 63, wid = tid >> 6;
    int wm = wid >> 1, wn = wid & 1;
    f32x4 acc[4][4];
    #pragma unroll
    for (int i = 0; i < 4; ++i)
        #pragma unroll
        for (int j2 = 0; j2 < 4; ++j2)
            acc[i][j2] = (f32x4)(0.f);

    const int srow = tid >> 2;
    const int scol = (tid & 3) * 8;
    const short* ga = A + (size_t)(m0 + srow) * Kd + scol;
    const short* gb = Bm + (size_t)(n0 + srow) * Kd + scol;
    short* la0 = &lA[tid * 8];
    short* la1 = &lA[64 * 32 + tid * 8];
    short* lb0 = &lB[tid * 8];
    short* lb1 = &lB[64 * 32 + tid * 8];

    int r = lane & 15, kc = (lane >> 4) * 8;

    for (int k0 = 0; k0 < Kd; k0 += 32) {
        __syncthreads();
        gload16(ga + k0, la0);
        gload16(ga + (size_t)64 * Kd + k0, la1);
        gload16(gb + k0, lb0);
        gload16(gb + (size_t)64 * Kd + k0, lb1);
        __syncthreads();
        short8v af[4], bf[4];
        #pragma unroll
        for (int f = 0; f < 4; ++f)
            af[f] = *(const short8v*)&lA[(wm * 64 + f * 16 + r) * 32 + kc];
        #pragma unroll
        for (int f = 0; f < 4; ++f)
            bf[f] = *(const short8v*)&lB[(wn * 64 + f * 16 + r) * 32 + kc];
        #pragma unroll
        for (int i = 0; i < 4; ++i)
            #pragma unroll
            for (int j2 = 0; j2 < 4; ++j2)
                acc[i][j2] = __builtin_amdgcn_mfma_f32_16x16x32_bf16(
                    af[i], bf[j2], acc[i][j2], 0, 0, 0);
    }

    int cr = (lane >> 4) * 4;
    int cc = lane & 15;
    float bv[4];
    #pragma unroll
    for (int j2 = 0; j2 < 4; ++j2)
        bv[j2] = bias[n0 + wn * 64 + j2 * 16 + cc];
    #pragma unroll
    for (int i = 0; i < 4; ++i) {
        #pragma unroll
        for (int rr = 0; rr < 4; ++rr) {
            int row = m0 + wm * 64 + i * 16 + cr + rr;
            int dr = rowmap[row];
            #pragma unroll
            for (int j2 = 0; j2 < 4; ++j2) {
                int col = n0 + wn * 64 + j2 * 16 + cc;
                float v = acc[i][j2][rr] + bv[j2];
                if (MODE == 0) {
                    if (col < 1536)
                        C0[(size_t)dr * 1536 + col] = (short)f2b(v);
                    else
                        C1[(size_t)row * 512 + (col - 1536)] = (short)f2b(v);
                } else {
                    Cf[(size_t)dr * N + col] = v;
                }
            }
        }
    }
}

// ---------- windowed attention v5: pow2 LDS strides + XOR bank swizzle ----------
// Block = 16 tokens x 4 heads (4 waves, wave = 1 head).
// lK[48][128], lV[48][256]: stride == 0 mod 32 dwords (rows don't shift banks);
// 16B-slot XOR swizzle col ^= ((row&7)<<3) applied at BOTH stage-write and read
// balances every gather across all 8 bank groups.
__global__ __launch_bounds__(256)
void attn5_kernel(const short* __restrict__ ext, const short* __restrict__ qb,
                  const int* __restrict__ extrow, short* __restrict__ o)
{
    __shared__ short lK[48 * 128];
    __shared__ short lV[48 * 256];
    __shared__ float ps[4][16][33];

    int bid = blockIdx.x;
    int swz = (bid & 7) * (gridDim.x >> 3) + (bid >> 3);  // XCD-contiguous
    int tg = swz >> 2, hg = swz & 3;
    int t0 = tg << 4, h0 = hg << 2;
    int r0 = extrow[t0] - 31;
    int tid = threadIdx.x;

    // ---- stage K: 48 rows x 128 cols (row 47 is a clamped dup, never read) ----
    #pragma unroll
    for (int p = 0; p < 3; ++p) {
        int idx = p * 2048 + tid * 8;
        int row = idx >> 7, col = idx & 127;
        int sr = r0 + (row < 47 ? row : 46);
        int dcol = col ^ ((row & 7) << 3);
        *(short8v*)&lK[row * 128 + dcol] =
            *(const short8v*)&ext[(size_t)sr * 1536 + h0 * 32 + col];
    }
    // ---- stage V: 48 rows x 256 cols ----
    #pragma unroll
    for (int p = 0; p < 6; ++p) {
        int idx = p * 2048 + tid * 8;
        int row = idx >> 8, col = idx & 255;
        int sr = r0 + (row < 47 ? row : 46);
        int dcol = col ^ ((row & 7) << 3);
        *(short8v*)&lV[row * 256 + dcol] =
            *(const short8v*)&ext[(size_t)sr * 1536 + 512 + h0 * 64 + col];
    }

    int wv = tid >> 6, lane = tid & 63;
    int ti = lane >> 2, q4 = lane & 3;
    int t = t0 + ti, h = h0 + wv;

    // Q into registers (issued before the barrier to hide latency)
    const short* qp = qb + (size_t)t * 512 + h * 32;
    uint4 qv0 = *(const uint4*)(qp);
    uint4 qv1 = *(const uint4*)(qp + 8);
    uint4 qv2 = *(const uint4*)(qp + 16);
    uint4 qv3 = *(const uint4*)(qp + 24);

    __syncthreads();

    // ---- QK: each lane does 8 window positions c = q4 + 4i ----
    float lg[8];
    #pragma unroll
    for (int i = 0; i < 8; ++i) {
        int c = q4 + i * 4;
        int lr = ti + 31 - c;
        int sw = (lr & 7) << 3;
        const short* kr = &lK[lr * 128];
        uint4 kk[4];
        kk[0] = *(const uint4*)&kr[(wv * 32 +  0) ^ sw];
        kk[1] = *(const uint4*)&kr[(wv * 32 +  8) ^ sw];
        kk[2] = *(const uint4*)&kr[(wv * 32 + 16) ^ sw];
        kk[3] = *(const uint4*)&kr[(wv * 32 + 24) ^ sw];
        uint4 qq[4] = {qv0, qv1, qv2, qv3};
        float a0 = 0.f, a1 = 0.f;
        #pragma unroll
        for (int w = 0; w < 4; ++w) {
            a0 = fmaf(blo(kk[w].x), blo(qq[w].x), a0);
            a1 = fmaf(bhi(kk[w].x), bhi(qq[w].x), a1);
            a0 = fmaf(blo(kk[w].y), blo(qq[w].y), a0);
            a1 = fmaf(bhi(kk[w].y), bhi(qq[w].y), a1);
            a0 = fmaf(blo(kk[w].z), blo(qq[w].z), a0);
            a1 = fmaf(bhi(kk[w].z), bhi(qq[w].z), a1);
            a0 = fmaf(blo(kk[w].w), blo(qq[w].w), a0);
            a1 = fmaf(bhi(kk[w].w), bhi(qq[w].w), a1);
        }
        lg[i] = (a0 + a1) * 0.17677669529663687f;
    }
    // softmax across 32 = 8 local x 4 lanes (q4 group)
    float m = lg[0];
    #pragma unroll
    for (int i = 1; i < 8; ++i) m = fmaxf(m, lg[i]);
    m = fmaxf(m, __shfl_xor(m, 1, 64));
    m = fmaxf(m, __shfl_xor(m, 2, 64));
    float s = 0.f;
    float pv[8];
    #pragma unroll
    for (int i = 0; i < 8; ++i) { pv[i] = __expf(lg[i] - m); s += pv[i]; }
    s += __shfl_xor(s, 1, 64);
    s += __shfl_xor(s, 2, 64);
    float inv = 1.f / s;
    #pragma unroll
    for (int i = 0; i < 8; ++i)
        ps[wv][ti][q4 + i * 4] = pv[i] * inv;

    __syncthreads();

    // ---- PV: lane (ti, q4) owns dv chunk q4*16 ----
    int dv0 = q4 * 16;
    float a[16];
    #pragma unroll
    for (int k = 0; k < 16; ++k) a[k] = 0.f;
    #pragma unroll
    for (int c = 0; c < 32; ++c) {
        int lr = ti + 31 - c;
        int sw = (lr & 7) << 3;
        float pc = ps[wv][ti][c];
        const short* vr = &lV[lr * 256];
        uint4 v0 = *(const uint4*)&vr[(wv * 64 + dv0    ) ^ sw];
        uint4 v1 = *(const uint4*)&vr[(wv * 64 + dv0 + 8) ^ sw];
        a[0]  = fmaf(pc, blo(v0.x), a[0]);
        a[1]  = fmaf(pc, bhi(v0.x), a[1]);
        a[2]  = fmaf(pc, blo(v0.y), a[2]);
        a[3]  = fmaf(pc, bhi(v0.y), a[3]);
        a[4]  = fmaf(pc, blo(v0.z), a[4]);
        a[5]  = fmaf(pc, bhi(v0.z), a[5]);
        a[6]  = fmaf(pc, blo(v0.w), a[6]);
        a[7]  = fmaf(pc, bhi(v0.w), a[7]);
        a[8]  = fmaf(pc, blo(v1.x), a[8]);
        a[9]  = fmaf(pc, bhi(v1.x), a[9]);
        a[10] = fmaf(pc, blo(v1.y), a[10]);
        a[11] = fmaf(pc, bhi(v1.y), a[11]);
        a[12] = fmaf(pc, blo(v1.z), a[12]);
        a[13] = fmaf(pc, bhi(v1.z), a[13]);
        a[14] = fmaf(pc, blo(v1.w), a[14]);
        a[15] = fmaf(pc, bhi(v1.w), a[15]);
    }
    unsigned ow[8];
    #pragma unroll
    for (int k = 0; k < 8; ++k)
        ow[k] = ((unsigned)f2b(a[2 * k + 1]) << 16) | (unsigned)f2b(a[2 * k]);
    short* op = o + (size_t)t * 1024 + h * 64 + dv0;
    uint4 s0 = {ow[0], ow[1], ow[2], ow[3]};
    uint4 s1 = {ow[4], ow[5], ow[6], ow[7]};
    *(uint4*)(op)     = s0;
    *(uint4*)(op + 8) = s1;
}

// ---------- host ----------
extern "C" void kernel_launch(void* const* d_in, const int* in_sizes, int n_in,
                              void* d_out, int out_size, void* d_ws, size_t ws_size,
                              hipStream_t stream)
{
    const float* x      = (const float*)d_in[0];
    const float* Wkv    = (const float*)d_in[1];
    const float* bkv    = (const float*)d_in[2];
    const float* Wq     = (const float*)d_in[3];
    const float* bq     = (const float*)d_in[4];
    const float* Wp     = (const float*)d_in[5];
    const float* bp     = (const float*)d_in[6];
    const float* buffer = (const float*)d_in[7];
    const int*   sl     = (const int*)d_in[8];

    int E  = in_sizes[6];          // 1024
    int Kc = in_sizes[4];          // 512
    int T  = in_sizes[0] / E;      // 4096
    int Bn = in_sizes[8];          // 8
    int EK = E + Kc;               // 1536
    int NKVQ = EK + Kc;            // 2048
    int MAXL = out_size / (Bn * E);
    int TEXT = T + 31 * Bn;        // 4344 ext rows

    size_t nX = (size_t)T * E, nWkv = (size_t)EK * E, nWq = (size_t)Kc * E;
    size_t nWp = (size_t)E * E, nBuf = (size_t)in_sizes[7];

    short* xb    = (short*)d_ws;
    short* wkvqb = xb + nX;                 // [2048,1024] merged weights
    short* wpb   = wkvqb + nWkv + nWq;
    short* qbuf  = wpb + nWp;               // [T,512]
    short* extb  = qbuf + (size_t)T * Kc;   // [TEXT,1536]
    short* ob    = extb + (size_t)TEXT * EK;
    int*   extrowp = (int*)(ob + (size_t)T * E);
    int*   destrow = extrowp + T;
    float* biascat = (float*)(destrow + T);

    float* y = (float*)d_out;

    long n0 = (long)nX, n1 = n0 + (long)nWkv, n2 = n1 + (long)nWq;
    long n3 = n2 + (long)nWp, n4 = n3 + (long)nBuf;
    int prep_blocks = (int)((n4 / 8 + 255) / 256);
    prep_kernel<<<prep_blocks, 256, 0, stream>>>(
        x, Wkv, Wq, Wp, buffer, sl, bkv, bq, xb, extb,
        extrowp, destrow, biascat,
        n0, n1, n2, n3, n4, T, Bn, MAXL, EK, NKVQ);

    padzero_kernel<<<Bn * MAXL, E / 4, 0, stream>>>(y, sl, MAXL, E);

    // merged kv+q projection; kv rows scatter into ext layout, q separate
    gemm_bt<0><<<(T / 128) * (NKVQ / 128), 256, 0, stream>>>(
        xb, wkvqb, biascat, extb, qbuf, nullptr, extrowp, T, NKVQ, E);

    attn5_kernel<<<(T / 16) * 4, 256, 0, stream>>>(extb, qbuf, extrowp, ob);

    gemm_bt<1><<<(T / 128) * (E / 128), 256, 0, stream>>>(
        ob, wpb, bp, nullptr, nullptr, y, destrow, T, E, E);
}

// Round 6
// 79.940 us; speedup vs baseline: 1.1363x; 1.1363x over previous
//
#include <hip/hip_runtime.h>

typedef __attribute__((ext_vector_type(8))) short short8v;
typedef __attribute__((ext_vector_type(4))) float f32x4;

// ---------- helpers ----------
__device__ inline unsigned short f2b(float f) {
    unsigned u = __builtin_bit_cast(unsigned, f);
    unsigned r = u + 0x7fffu + ((u >> 16) & 1u);
    return (unsigned short)(r >> 16);
}
__device__ inline void gload16(const void* g, void* l) {
    __builtin_amdgcn_global_load_lds(
        (const __attribute__((address_space(1))) void*)g,
        (__attribute__((address_space(3))) void*)l, 16, 0, 0);
}

// ---------- prep: f32->bf16 conversion + ext prefixes + row maps ----------
__global__ __launch_bounds__(256)
void prep_kernel(const float* __restrict__ x, const float* __restrict__ wkv,
                 const float* __restrict__ wq, const float* __restrict__ wp,
                 const float* __restrict__ buf, const int* __restrict__ sl,
                 const float* __restrict__ bkv, const float* __restrict__ bq,
                 short* __restrict__ dst, short* __restrict__ ext,
                 int* __restrict__ extrow, int* __restrict__ destrow,
                 float* __restrict__ biascat,
                 long n0, long n1, long n2, long n3, long n4,
                 int T, int Bn, int MAXL, int EK, int NKVQ)
{
    long gid = (long)blockIdx.x * blockDim.x + threadIdx.x;
    long e = gid * 8;
    if (e < n3) {
        const float* s; long off;
        if (e < n0)      { s = x;   off = e; }
        else if (e < n1) { s = wkv; off = e - n0; }
        else if (e < n2) { s = wq;  off = e - n1; }
        else             { s = wp;  off = e - n2; }
        float4 a = *(const float4*)(s + off);
        float4 b = *(const float4*)(s + off + 4);
        short8v o;
        o[0] = (short)f2b(a.x); o[1] = (short)f2b(a.y);
        o[2] = (short)f2b(a.z); o[3] = (short)f2b(a.w);
        o[4] = (short)f2b(b.x); o[5] = (short)f2b(b.y);
        o[6] = (short)f2b(b.z); o[7] = (short)f2b(b.w);
        *(short8v*)(dst + e) = o;
    } else if (e < n4) {
        // learned buffer rows -> 31-row prefix of every segment in ext
        long off = e - n3;
        int brow = (int)(off / EK);
        int bcol = (int)(off % EK);
        float4 a = *(const float4*)(buf + off);
        float4 b = *(const float4*)(buf + off + 4);
        short8v o;
        o[0] = (short)f2b(a.x); o[1] = (short)f2b(a.y);
        o[2] = (short)f2b(a.z); o[3] = (short)f2b(a.w);
        o[4] = (short)f2b(b.x); o[5] = (short)f2b(b.y);
        o[6] = (short)f2b(b.z); o[7] = (short)f2b(b.w);
        int start = 0;
        for (int s = 0; s < 8; ++s) {
            int dr = 31 * s + start + brow;
            *(short8v*)&ext[(size_t)dr * EK + bcol] = o;
            start += sl[s];
        }
    }
    if (gid < T) {
        int start = 0, seg = 0, jloc = 0;
        for (int i = 0; i < Bn; ++i) {
            int len = sl[i];
            if (gid >= start && gid < start + len) { seg = i; jloc = (int)gid - start; }
            start += len;
        }
        destrow[gid] = seg * MAXL + jloc;
        extrow[gid]  = 31 * (seg + 1) + (int)gid;
    }
    if (gid < NKVQ) {
        biascat[gid] = (gid < EK) ? bkv[gid] : bq[gid - EK];
    }
}

// ---------- zero only the padding rows of y ----------
__global__ __launch_bounds__(256)
void padzero_kernel(float* __restrict__ y, const int* __restrict__ sl,
                    int MAXL, int E)
{
    int row = blockIdx.x;
    int seg = row / MAXL, pos = row - seg * MAXL;
    if (pos < sl[seg]) return;
    float4 z = {0.f, 0.f, 0.f, 0.f};
    *(float4*)&y[(size_t)row * E + threadIdx.x * 4] = z;
}

// ---------- bf16 GEMM, 2-phase double-buffered: C = A @ B^T + bias ----------
// MODE 0: split write: col<1536 -> bf16 ext[rowmap[row]][col]; else q[row][col-1536]
// MODE 1: f32 rows scattered: y[rowmap[row]][col]
template<int MODE>
__global__ __launch_bounds__(256)
void gemm_bt(const short* __restrict__ A, const short* __restrict__ Bm,
             const float* __restrict__ bias,
             short* __restrict__ C0, short* __restrict__ C1,
             float* __restrict__ Cf, const int* __restrict__ rowmap,
             int M, int N, int Kd)
{
    __shared__ short lA[2][128 * 32];
    __shared__ short lB[2][128 * 32];
    int nb = N >> 7;
    // XCD-aware bijective swizzle (grid is a multiple of 8)
    int bid0 = blockIdx.x;
    int bid = (bid0 & 7) * ((int)gridDim.x >> 3) + (bid0 >> 3);
    int m0 = (bid / nb) << 7, n0 = (bid % nb) << 7;
    int tid = threadIdx.x;
    int lane = tid & 63, wid = tid >> 6;
    int wm = wid >> 1, wn = wid & 1;
    f32x4 acc[4][4];
    #pragma unroll
    for (int i = 0; i < 4; ++i)
        #pragma unroll
        for (int j2 = 0; j2 < 4; ++j2)
            acc[i][j2] = (f32x4)(0.f);

    const int srow = tid >> 2;
    const int scol = (tid & 3) * 8;
    const short* ga = A + (size_t)(m0 + srow) * Kd + scol;
    const short* gb = Bm + (size_t)(n0 + srow) * Kd + scol;

    auto stage = [&](int bf2, int k0) {
        gload16(ga + k0, &lA[bf2][tid * 8]);
        gload16(ga + (size_t)64 * Kd + k0, &lA[bf2][64 * 32 + tid * 8]);
        gload16(gb + k0, &lB[bf2][tid * 8]);
        gload16(gb + (size_t)64 * Kd + k0, &lB[bf2][64 * 32 + tid * 8]);
    };

    int r = lane & 15, kc = (lane >> 4) * 8;
    int nk = Kd >> 5;

    stage(0, 0);
    for (int t = 0; t < nk; ++t) {
        __syncthreads();                        // vmcnt drain + barrier
        if (t + 1 < nk) stage((t + 1) & 1, (t + 1) << 5);
        int cb = t & 1;
        short8v af[4], bf[4];
        #pragma unroll
        for (int f = 0; f < 4; ++f)
            af[f] = *(const short8v*)&lA[cb][(wm * 64 + f * 16 + r) * 32 + kc];
        #pragma unroll
        for (int f = 0; f < 4; ++f)
            bf[f] = *(const short8v*)&lB[cb][(wn * 64 + f * 16 + r) * 32 + kc];
        #pragma unroll
        for (int i = 0; i < 4; ++i)
            #pragma unroll
            for (int j2 = 0; j2 < 4; ++j2)
                acc[i][j2] = __builtin_amdgcn_mfma_f32_16x16x32_bf16(
                    af[i], bf[j2], acc[i][j2], 0, 0, 0);
    }

    int cr = (lane >> 4) * 4;
    int cc = lane & 15;
    float bv[4];
    #pragma unroll
    for (int j2 = 0; j2 < 4; ++j2)
        bv[j2] = bias[n0 + wn * 64 + j2 * 16 + cc];
    #pragma unroll
    for (int i = 0; i < 4; ++i) {
        #pragma unroll
        for (int rr = 0; rr < 4; ++rr) {
            int row = m0 + wm * 64 + i * 16 + cr + rr;
            int dr = rowmap[row];
            #pragma unroll
            for (int j2 = 0; j2 < 4; ++j2) {
                int col = n0 + wn * 64 + j2 * 16 + cc;
                float v = acc[i][j2][rr] + bv[j2];
                if (MODE == 0) {
                    if (col < 1536)
                        C0[(size_t)dr * 1536 + col] = (short)f2b(v);
                    else
                        C1[(size_t)row * 512 + (col - 1536)] = (short)f2b(v);
                } else {
                    Cf[(size_t)dr * N + col] = v;
                }
            }
        }
    }
}

// ---------- windowed attention v6: MFMA ----------
// Block = 16 tokens x 4 heads (4 waves; wave = 1 head).
// Per wave: S[16,48] = Q[16,32]@K[48,32]^T (3 mfma_16x16x32_bf16),
// band-masked softmax in registers (cross-lane over lane&15),
// P (bf16) -> LDS, O[16,64] = P[16,64]@V[64,64] (8 mfma).
// Fragment layouts identical to the verified GEMM:
//   A row = lane&15, k = (lane>>4)*8+j ; B col = lane&15, same k-slice;
//   D col = lane&15, row = (lane>>4)*4+reg.
__global__ __launch_bounds__(256)
void attn6_kernel(const short* __restrict__ ext, const short* __restrict__ qb,
                  const int* __restrict__ extrow, short* __restrict__ o)
{
    __shared__ short lK[4 * 48 * 40];   // [head][row<48][40]  (pad 32->40)
    __shared__ short lV[4 * 48 * 66];   // [head][row<48][66]  (pad 64->66)
    __shared__ short ps[4 * 16 * 76];   // [head][ti][76] bf16 P (pad 64->76)

    int bid = blockIdx.x;
    int swz = (bid & 7) * (gridDim.x >> 3) + (bid >> 3);  // XCD-contiguous
    int tg = swz >> 2, hg = swz & 3;
    int t0 = tg << 4, h0 = hg << 2;
    int r0 = extrow[t0] - 31;
    int tid = threadIdx.x;
    int wv = tid >> 6, lane = tid & 63;

    // ---- stage K: 4 heads x 48 rows x 32 shorts ----
    #pragma unroll
    for (int p = 0; p < 3; ++p) {
        int q = p * 256 + tid;              // 0..767
        int hd = q / 192;
        int rem = q - hd * 192;
        int rr = rem >> 2, cc = rem & 3;
        int sr = r0 + (rr < 47 ? rr : 46);
        *(short8v*)&lK[hd * 1920 + rr * 40 + cc * 8] =
            *(const short8v*)&ext[(size_t)sr * 1536 + (h0 + hd) * 32 + cc * 8];
    }
    // ---- stage V: 4 heads x 48 rows x 64 shorts ----
    #pragma unroll
    for (int p = 0; p < 6; ++p) {
        int q = p * 256 + tid;              // 0..1535
        int hd = q / 384;
        int rem = q - hd * 384;
        int rr = rem >> 3, cc = rem & 7;
        int sr = r0 + (rr < 47 ? rr : 46);
        *(short8v*)&lV[hd * 3168 + rr * 66 + cc * 8] =
            *(const short8v*)&ext[(size_t)sr * 1536 + 512 + (h0 + hd) * 64 + cc * 8];
    }
    // ---- zero ps cols 48..63 (A-operand tail of PV k-tile 1) ----
    if (tid < 128) {
        int hd = tid >> 5, row = (tid >> 1) & 15, hf = tid & 1;
        uint4 z = {0u, 0u, 0u, 0u};
        *(uint4*)&ps[hd * 1216 + row * 76 + 48 + hf * 8] = z;
    }

    int h = h0 + wv;
    int nlo = lane & 15, g4 = lane >> 4;

    // Q A-fragment straight from global (16 rows, L2-resident)
    short8v aq = *(const short8v*)&qb[(size_t)(t0 + nlo) * 512 + h * 32 + g4 * 8];

    __syncthreads();

    // ---- QK^T: 3 MFMAs -> S[token][lr] ----
    f32x4 sg[3];
    #pragma unroll
    for (int g = 0; g < 3; ++g) {
        short8v bk = *(const short8v*)&lK[wv * 1920 + (g * 16 + nlo) * 40 + g4 * 8];
        f32x4 z = (f32x4)(0.f);
        sg[g] = __builtin_amdgcn_mfma_f32_16x16x32_bf16(aq, bk, z, 0, 0, 0);
    }

    // ---- band-masked softmax; write bf16 P to LDS ----
    // lane holds S[tk = g4*4+r][lr = g*16+nlo]; valid iff tk <= lr <= tk+31.
    // tile1 always valid; tile0 valid iff nlo>=tk; tile2 valid iff nlo<tk.
    const float scale = 0.17677669529663687f;
    #pragma unroll
    for (int r = 0; r < 4; ++r) {
        int tk = g4 * 4 + r;
        bool v0 = (nlo >= tk);
        bool v2 = (nlo < tk);
        float s0 = v0 ? sg[0][r] * scale : -1e30f;
        float s1 = sg[1][r] * scale;
        float s2 = v2 ? sg[2][r] * scale : -1e30f;
        float m = fmaxf(fmaxf(s0, s1), s2);
        m = fmaxf(m, __shfl_xor(m, 1, 64));
        m = fmaxf(m, __shfl_xor(m, 2, 64));
        m = fmaxf(m, __shfl_xor(m, 4, 64));
        m = fmaxf(m, __shfl_xor(m, 8, 64));
        float p0 = v0 ? __expf(s0 - m) : 0.f;
        float p1 = __expf(s1 - m);
        float p2 = v2 ? __expf(s2 - m) : 0.f;
        float sm = p0 + p1 + p2;
        sm += __shfl_xor(sm, 1, 64);
        sm += __shfl_xor(sm, 2, 64);
        sm += __shfl_xor(sm, 4, 64);
        sm += __shfl_xor(sm, 8, 64);
        float inv = 1.f / sm;
        short* pr = &ps[wv * 1216 + tk * 76];
        pr[nlo]      = (short)f2b(p0 * inv);
        pr[16 + nlo] = (short)f2b(p1 * inv);
        pr[32 + nlo] = (short)f2b(p2 * inv);
    }

    // ---- PV: O[16,64] = P[16,64]@V[64,64] (compiler inserts lgkm waits) ----
    short8v pa0 = *(const short8v*)&ps[wv * 1216 + nlo * 76 + g4 * 8];
    short8v pa1 = *(const short8v*)&ps[wv * 1216 + nlo * 76 + 32 + g4 * 8];
    #pragma unroll
    for (int dvt = 0; dvt < 4; ++dvt) {
        f32x4 acc = (f32x4)(0.f);
        short8v b0, b1;
        #pragma unroll
        for (int j = 0; j < 8; ++j) {
            int lr = g4 * 8 + j;
            b0[j] = lV[wv * 3168 + lr * 66 + dvt * 16 + nlo];
        }
        acc = __builtin_amdgcn_mfma_f32_16x16x32_bf16(pa0, b0, acc, 0, 0, 0);
        #pragma unroll
        for (int j = 0; j < 8; ++j) {
            int lr = 32 + g4 * 8 + j;
            int rowc = lr < 47 ? lr : 47;    // clamp; P=0 there anyway
            b1[j] = lV[wv * 3168 + rowc * 66 + dvt * 16 + nlo];
        }
        acc = __builtin_amdgcn_mfma_f32_16x16x32_bf16(pa1, b1, acc, 0, 0, 0);
        #pragma unroll
        for (int r = 0; r < 4; ++r) {
            int t = t0 + g4 * 4 + r;
            o[(size_t)t * 1024 + h * 64 + dvt * 16 + nlo] = (short)f2b(acc[r]);
        }
    }
}

// ---------- host ----------
extern "C" void kernel_launch(void* const* d_in, const int* in_sizes, int n_in,
                              void* d_out, int out_size, void* d_ws, size_t ws_size,
                              hipStream_t stream)
{
    const float* x      = (const float*)d_in[0];
    const float* Wkv    = (const float*)d_in[1];
    const float* bkv    = (const float*)d_in[2];
    const float* Wq     = (const float*)d_in[3];
    const float* bq     = (const float*)d_in[4];
    const float* Wp     = (const float*)d_in[5];
    const float* bp     = (const float*)d_in[6];
    const float* buffer = (const float*)d_in[7];
    const int*   sl     = (const int*)d_in[8];

    int E  = in_sizes[6];          // 1024
    int Kc = in_sizes[4];          // 512
    int T  = in_sizes[0] / E;      // 4096
    int Bn = in_sizes[8];          // 8
    int EK = E + Kc;               // 1536
    int NKVQ = EK + Kc;            // 2048
    int MAXL = out_size / (Bn * E);
    int TEXT = T + 31 * Bn;        // 4344 ext rows

    size_t nX = (size_t)T * E, nWkv = (size_t)EK * E, nWq = (size_t)Kc * E;
    size_t nWp = (size_t)E * E, nBuf = (size_t)in_sizes[7];

    short* xb    = (short*)d_ws;
    short* wkvqb = xb + nX;                 // [2048,1024] merged weights
    short* wpb   = wkvqb + nWkv + nWq;
    short* qbuf  = wpb + nWp;               // [T,512]
    short* extb  = qbuf + (size_t)T * Kc;   // [TEXT,1536]
    short* ob    = extb + (size_t)TEXT * EK;
    int*   extrowp = (int*)(ob + (size_t)T * E);
    int*   destrow = extrowp + T;
    float* biascat = (float*)(destrow + T);

    float* y = (float*)d_out;

    long n0 = (long)nX, n1 = n0 + (long)nWkv, n2 = n1 + (long)nWq;
    long n3 = n2 + (long)nWp, n4 = n3 + (long)nBuf;
    int prep_blocks = (int)((n4 / 8 + 255) / 256);
    prep_kernel<<<prep_blocks, 256, 0, stream>>>(
        x, Wkv, Wq, Wp, buffer, sl, bkv, bq, xb, extb,
        extrowp, destrow, biascat,
        n0, n1, n2, n3, n4, T, Bn, MAXL, EK, NKVQ);

    padzero_kernel<<<Bn * MAXL, E / 4, 0, stream>>>(y, sl, MAXL, E);

    // merged kv+q projection; kv rows scatter into ext layout, q separate
    gemm_bt<0><<<(T / 128) * (NKVQ / 128), 256, 0, stream>>>(
        xb, wkvqb, biascat, extb, qbuf, nullptr, extrowp, T, NKVQ, E);

    attn6_kernel<<<(T / 16) * 4, 256, 0, stream>>>(extb, qbuf, extrowp, ob);

    gemm_bt<1><<<(T / 128) * (E / 128), 256, 0, stream>>>(
        ob, wpb, bp, nullptr, nullptr, y, destrow, T, E, E);
}